// Round 5
// baseline (160.725 us; speedup 1.0000x reference)
//
#include <hip/hip_runtime.h>
#include <hip/hip_bf16.h>
#include <hip/hip_fp16.h>

#define N_NODES 4096
#define F_IN    512
#define HC      512   // H*C
#define H_HEADS 8
#define C_DIM   64
#define NCLS    16
#define CAP     192
#define NEG_SLOPE 0.2f

typedef __bf16 bf16x8 __attribute__((ext_vector_type(8)));
typedef float  f32x4  __attribute__((ext_vector_type(4)));
typedef unsigned short us8 __attribute__((ext_vector_type(8)));

#define GT 256   // gemm1 tiles: 32 m-tiles (128 rows) x 8 heads (64 cols); b = head*32 + m

// Staged W layout (from k_wsplit): chunk(rg,kb) at ushort offset (rg*16+kb)*512;
// lane l holds 8 ushorts for col rg*16+(l&15), k = kb*32+(l>>4)*8. global_load_lds
// stages chunk_base+lane*16B (coalesced), image == MFMA B-fragment order.
// A (x) is converted on the fly: coalesced float4 loads + in-register bf16 hi/lo
// split + ds_write_b128 into the same fragment order.

// ------- kernel 0: split + transpose W1 -> staged bf16 hi/lo (64 blocks) -------
__global__ __launch_bounds__(256) void k_wsplit(const float* __restrict__ W,
                                                ushort* __restrict__ whiT,
                                                ushort* __restrict__ wloT) {
    __shared__ float tile[64][65];
    int bb = blockIdx.x;
    int t = threadIdx.x;
    int n0 = (bb & 7) * 64, k0 = (bb >> 3) * 64;
#pragma unroll
    for (int i = 0; i < 4; ++i) {
        int r = i * 16 + (t >> 4);
        int c = (t & 15) * 4;
        *(float4*)&tile[r][c] = *(const float4*)&W[(size_t)(k0 + r) * HC + n0 + c];
    }
    __syncthreads();
    int rg_local = t >> 6;
    int l = t & 63;
    int n_local = rg_local * 16 + (l & 15);
#pragma unroll
    for (int kb_local = 0; kb_local < 2; ++kb_local) {
        int k_local = kb_local * 32 + (l >> 4) * 8;
        us8 hv, lv;
#pragma unroll
        for (int u = 0; u < 8; ++u) {
            float f = tile[k_local + u][n_local];
            __bf16 h = (__bf16)f;
            __bf16 lo_ = (__bf16)(f - (float)h);
            hv[u] = __builtin_bit_cast(unsigned short, h);
            lv[u] = __builtin_bit_cast(unsigned short, lo_);
        }
        int rg = (n0 >> 4) + rg_local;
        int kb = (k0 >> 5) + kb_local;
        size_t off = ((size_t)(rg * 16 + kb) * 64 + l) * 8;
        *(us8*)&whiT[off] = hv;
        *(us8*)&wloT[off] = lv;
    }
}

// ------- kernel 1: GEMM1 128x64 tiles (A on-the-fly split, B global_load_lds) + attn scalars | CSR -------
__global__ __launch_bounds__(256) void k_gemm1(const float* __restrict__ x,
                                               const ushort* __restrict__ Bhi,
                                               const ushort* __restrict__ Blo,
                                               const float* __restrict__ att_src,
                                               const float* __restrict__ att_dst,
                                               const float* __restrict__ adj,
                                               __half* __restrict__ C,
                                               float* __restrict__ a_src,
                                               float* __restrict__ a_dst,
                                               int* __restrict__ row_cnt,
                                               int* __restrict__ col_idx) {
    __shared__ __align__(16) ushort sAhi[4096], sAlo[4096], sBhi[2048], sBlo[2048];
    __shared__ float s_s[2][128], s_d[2][128];
    __shared__ int cnt_s;
    int b = blockIdx.x;
    int t = threadIdx.x;
    if (b >= GT) {
        // ---- CSR build (adds self loop); pure HBM stream overlapping the GEMM ----
        int i = b - GT;
        if (t == 0) cnt_s = 0;
        __syncthreads();
        const float4* row = (const float4*)(adj + (size_t)i * N_NODES);
        int* cols = col_idx + (size_t)i * CAP;
#pragma unroll
        for (int it = 0; it < 4; ++it) {
            int idx4 = it * 256 + t;
            float4 v = row[idx4];
            int j0 = idx4 * 4;
            if (v.x != 0.f && j0 + 0 != i) { int p = atomicAdd(&cnt_s, 1); if (p < CAP - 1) cols[p] = j0 + 0; }
            if (v.y != 0.f && j0 + 1 != i) { int p = atomicAdd(&cnt_s, 1); if (p < CAP - 1) cols[p] = j0 + 1; }
            if (v.z != 0.f && j0 + 2 != i) { int p = atomicAdd(&cnt_s, 1); if (p < CAP - 1) cols[p] = j0 + 2; }
            if (v.w != 0.f && j0 + 3 != i) { int p = atomicAdd(&cnt_s, 1); if (p < CAP - 1) cols[p] = j0 + 3; }
        }
        __syncthreads();
        if (t == 0) {
            int p = min(cnt_s, CAP - 1);
            cols[p] = i;
            row_cnt[i] = p + 1;
        }
        return;
    }
    int w = t >> 6, lane = t & 63;
    int head = b >> 5;                 // 8 head-blocks per m are 32 apart -> same XCD (x L2 reuse)
    int n0 = head * 64;
    int m0 = (b & 31) * 128;
    int mh = w & 1, nh = w >> 1;       // wave covers rows mh*64..+63, cols nh*32..+31
    f32x4 acc[4][2] = {};
    for (int kb = 0; kb < 16; ++kb) {
        // ---- B stage: 1KB chunk per wave per buffer via global_load_lds ----
        {
            size_t off = ((size_t)((head * 4 + w) * 16 + kb) * 64 + lane) * 8;
            __builtin_amdgcn_global_load_lds(
                (const __attribute__((address_space(1))) void*)(Bhi + off),
                (__attribute__((address_space(3))) void*)&sBhi[w * 512], 16, 0, 0);
            __builtin_amdgcn_global_load_lds(
                (const __attribute__((address_space(1))) void*)(Blo + off),
                (__attribute__((address_space(3))) void*)&sBlo[w * 512], 16, 0, 0);
        }
        // ---- A stage: rows 32w..32w+31, on-the-fly f32 -> bf16 hi/lo ----
#pragma unroll
        for (int gg = 0; gg < 2; ++gg) {
            int g = 2 * w + gg;
            int row = m0 + g * 16 + (lane & 15);
            int kk = kb * 32 + (lane >> 4) * 8;
            const float* src = &x[(size_t)row * F_IN + kk];
            float4 v0 = *(const float4*)&src[0];
            float4 v1 = *(const float4*)&src[4];
            float f[8] = {v0.x, v0.y, v0.z, v0.w, v1.x, v1.y, v1.z, v1.w};
            us8 hv, lv;
#pragma unroll
            for (int u = 0; u < 8; ++u) {
                __bf16 h = (__bf16)f[u];
                __bf16 lo_ = (__bf16)(f[u] - (float)h);
                hv[u] = __builtin_bit_cast(unsigned short, h);
                lv[u] = __builtin_bit_cast(unsigned short, lo_);
            }
            *(us8*)&sAhi[g * 512 + lane * 8] = hv;
            *(us8*)&sAlo[g * 512 + lane * 8] = lv;
        }
        __syncthreads();
        bf16x8 ahi[4], alo[4], bhi[2], blo[2];
#pragma unroll
        for (int mi = 0; mi < 4; ++mi) {
            int g = mh * 4 + mi;
            ahi[mi] = __builtin_bit_cast(bf16x8, *(const us8*)&sAhi[g * 512 + lane * 8]);
            alo[mi] = __builtin_bit_cast(bf16x8, *(const us8*)&sAlo[g * 512 + lane * 8]);
        }
#pragma unroll
        for (int ni = 0; ni < 2; ++ni) {
            int g = nh * 2 + ni;
            bhi[ni] = __builtin_bit_cast(bf16x8, *(const us8*)&sBhi[g * 512 + lane * 8]);
            blo[ni] = __builtin_bit_cast(bf16x8, *(const us8*)&sBlo[g * 512 + lane * 8]);
        }
#pragma unroll
        for (int mi = 0; mi < 4; ++mi)
#pragma unroll
            for (int ni = 0; ni < 2; ++ni) {
                acc[mi][ni] = __builtin_amdgcn_mfma_f32_16x16x32_bf16(ahi[mi], bhi[ni], acc[mi][ni], 0, 0, 0);
                acc[mi][ni] = __builtin_amdgcn_mfma_f32_16x16x32_bf16(alo[mi], bhi[ni], acc[mi][ni], 0, 0, 0);
                acc[mi][ni] = __builtin_amdgcn_mfma_f32_16x16x32_bf16(ahi[mi], blo[ni], acc[mi][ni], 0, 0, 0);
            }
        __syncthreads();
    }
    int r0 = (lane >> 4) * 4;
    int cn = lane & 15;
    // fused attention scalars: per-row dot with att vectors
    float as0 = att_src[n0 + nh * 32 + cn],      as1 = att_src[n0 + nh * 32 + 16 + cn];
    float ad0 = att_dst[n0 + nh * 32 + cn],      ad1 = att_dst[n0 + nh * 32 + 16 + cn];
#pragma unroll
    for (int mi = 0; mi < 4; ++mi)
#pragma unroll
        for (int r = 0; r < 4; ++r) {
            float ps = acc[mi][0][r] * as0 + acc[mi][1][r] * as1;
            float pd = acc[mi][0][r] * ad0 + acc[mi][1][r] * ad1;
#pragma unroll
            for (int o = 1; o < 16; o <<= 1) {
                ps += __shfl_xor(ps, o, 64);
                pd += __shfl_xor(pd, o, 64);
            }
            if (cn == 0) {
                int row = mh * 64 + mi * 16 + r0 + r;
                s_s[nh][row] = ps;
                s_d[nh][row] = pd;
            }
        }
    // C store (fp16)
#pragma unroll
    for (int mi = 0; mi < 4; ++mi)
#pragma unroll
        for (int ni = 0; ni < 2; ++ni) {
            size_t base = (size_t)(m0 + mh * 64 + mi * 16 + r0) * HC + (n0 + nh * 32 + ni * 16 + cn);
#pragma unroll
            for (int r = 0; r < 4; ++r)
                C[base + (size_t)r * HC] = __float2half(acc[mi][ni][r]);
        }
    __syncthreads();
    if (t < 128) {
        a_src[(m0 + t) * H_HEADS + head] = s_s[0][t] + s_s[1][t];
        a_dst[(m0 + t) * H_HEADS + head] = s_d[0][t] + s_d[1][t];
    }
}

// ------- kernel 2: layer-1 softmax aggregation + bias + ELU + fused GEMM2 + layer-2 scalars -------
__global__ __launch_bounds__(256) void k_agg1(const __half* __restrict__ hf,
                                              const float* __restrict__ a_src,
                                              const float* __restrict__ a_dst,
                                              const int* __restrict__ row_cnt,
                                              const int* __restrict__ col_idx,
                                              const float* __restrict__ b1,
                                              const float* __restrict__ W2,       // [512,16]
                                              const float* __restrict__ att_src2, // [16]
                                              const float* __restrict__ att_dst2, // [16]
                                              float* __restrict__ h2,
                                              float* __restrict__ a_src2,
                                              float* __restrict__ a_dst2) {
    int i = blockIdx.x;
    int t = threadIdx.x;
    __shared__ float wL[CAP][H_HEADS];
    __shared__ int   colL[CAP];
    __shared__ float denom[H_HEADS];
    __shared__ float ad[H_HEADS];
    __shared__ float elu_s[HC];
    __shared__ float part[16][17];
    int cnt = row_cnt[i];
    if (t < H_HEADS) ad[t] = a_dst[i * H_HEADS + t];
    for (int j = t; j < cnt; j += 256) colL[j] = col_idx[(size_t)i * CAP + j];
    __syncthreads();
    for (int idx = t; idx < cnt * H_HEADS; idx += 256) {
        int j = idx >> 3, h = idx & 7;
        float l = a_src[colL[j] * H_HEADS + h] + ad[h];
        l = (l > 0.f) ? l : NEG_SLOPE * l;
        wL[j][h] = __expf(l);
    }
    __syncthreads();
    {
        int h = t >> 5, l32 = t & 31;
        float s = 0.f;
        for (int j = l32; j < cnt; j += 32) s += wL[j][h];
#pragma unroll
        for (int o = 16; o > 0; o >>= 1) s += __shfl_down(s, o, 32);
        if (l32 == 0) denom[h] = s;
    }
    __syncthreads();
    int e = t * 2;
    int h = e >> 6;
    float ax = 0.f, ay = 0.f;
    int j = 0;
    for (; j + 8 <= cnt; j += 8) {
        int c0 = colL[j],     c1 = colL[j + 1], c2 = colL[j + 2], c3 = colL[j + 3];
        int c4 = colL[j + 4], c5 = colL[j + 5], c6 = colL[j + 6], c7 = colL[j + 7];
        float2 v0 = __half22float2(*(const __half2*)&hf[(size_t)c0 * HC + e]);
        float2 v1 = __half22float2(*(const __half2*)&hf[(size_t)c1 * HC + e]);
        float2 v2 = __half22float2(*(const __half2*)&hf[(size_t)c2 * HC + e]);
        float2 v3 = __half22float2(*(const __half2*)&hf[(size_t)c3 * HC + e]);
        float2 v4 = __half22float2(*(const __half2*)&hf[(size_t)c4 * HC + e]);
        float2 v5 = __half22float2(*(const __half2*)&hf[(size_t)c5 * HC + e]);
        float2 v6 = __half22float2(*(const __half2*)&hf[(size_t)c6 * HC + e]);
        float2 v7 = __half22float2(*(const __half2*)&hf[(size_t)c7 * HC + e]);
        float w0 = wL[j][h],     w1 = wL[j + 1][h], w2 = wL[j + 2][h], w3 = wL[j + 3][h];
        float w4 = wL[j + 4][h], w5 = wL[j + 5][h], w6 = wL[j + 6][h], w7 = wL[j + 7][h];
        ax += w0 * v0.x + w1 * v1.x + w2 * v2.x + w3 * v3.x
            + w4 * v4.x + w5 * v5.x + w6 * v6.x + w7 * v7.x;
        ay += w0 * v0.y + w1 * v1.y + w2 * v2.y + w3 * v3.y
            + w4 * v4.y + w5 * v5.y + w6 * v6.y + w7 * v7.y;
    }
    for (; j + 4 <= cnt; j += 4) {
        int c0 = colL[j], c1 = colL[j + 1], c2 = colL[j + 2], c3 = colL[j + 3];
        float2 v0 = __half22float2(*(const __half2*)&hf[(size_t)c0 * HC + e]);
        float2 v1 = __half22float2(*(const __half2*)&hf[(size_t)c1 * HC + e]);
        float2 v2 = __half22float2(*(const __half2*)&hf[(size_t)c2 * HC + e]);
        float2 v3 = __half22float2(*(const __half2*)&hf[(size_t)c3 * HC + e]);
        float w0 = wL[j][h], w1 = wL[j + 1][h], w2 = wL[j + 2][h], w3 = wL[j + 3][h];
        ax += w0 * v0.x + w1 * v1.x + w2 * v2.x + w3 * v3.x;
        ay += w0 * v0.y + w1 * v1.y + w2 * v2.y + w3 * v3.y;
    }
    for (; j < cnt; ++j) {
        int c0 = colL[j];
        float2 v0 = __half22float2(*(const __half2*)&hf[(size_t)c0 * HC + e]);
        float w0 = wL[j][h];
        ax += w0 * v0.x;
        ay += w0 * v0.y;
    }
    float inv = 1.f / denom[h];
    float o0 = ax * inv + b1[e];
    float o1 = ay * inv + b1[e + 1];
    o0 = (o0 > 0.f) ? o0 : (__expf(o0) - 1.f);
    o1 = (o1 > 0.f) ? o1 : (__expf(o1) - 1.f);
    elu_s[e]     = o0;
    elu_s[e + 1] = o1;
    __syncthreads();
    // ---- fused GEMM2: h2[i,:] = elu_row @ W2  (512x16) ----
    int kg = t >> 4, c = t & 15;
    float p = 0.f;
    const float* w2p = W2 + (size_t)kg * 32 * NCLS + c;
    const float* es  = &elu_s[kg * 32];
#pragma unroll 8
    for (int kk = 0; kk < 32; ++kk) p += es[kk] * w2p[kk * NCLS];
    part[kg][c] = p;
    __syncthreads();
    if (t < 16) {
        float s = 0.f;
#pragma unroll
        for (int r = 0; r < 16; ++r) s += part[r][t];
        h2[(size_t)i * NCLS + t] = s;
        float vs = s * att_src2[t], vd = s * att_dst2[t];
#pragma unroll
        for (int o = 8; o > 0; o >>= 1) {
            vs += __shfl_xor(vs, o, 64);
            vd += __shfl_xor(vd, o, 64);
        }
        if (t == 0) { a_src2[i] = vs; a_dst2[i] = vd; }
    }
}

// ------- kernel 3: layer-2 softmax aggregation -------
__global__ __launch_bounds__(256) void k_agg2(const float* __restrict__ h2,
                                              const float* __restrict__ a_src2,
                                              const float* __restrict__ a_dst2,
                                              const int* __restrict__ row_cnt,
                                              const int* __restrict__ col_idx,
                                              const float* __restrict__ b2,
                                              float* __restrict__ out) {
    int t = threadIdx.x;
    int w = t >> 6, lane = t & 63;
    int i = blockIdx.x * 4 + w;
    __shared__ float ew[4][CAP];
    __shared__ int   colL[4][CAP];
    int cnt = row_cnt[i];
    float adi = a_dst2[i];
    float sum = 0.f;
    for (int j = lane; j < cnt; j += 64) {
        int col = col_idx[(size_t)i * CAP + j];
        colL[w][j] = col;
        float l = a_src2[col] + adi;
        l = (l > 0.f) ? l : NEG_SLOPE * l;
        float e = __expf(l);
        ew[w][j] = e;
        sum += e;
    }
#pragma unroll
    for (int o = 32; o > 0; o >>= 1) sum += __shfl_xor(sum, o, 64);
    int q = lane >> 4, c = lane & 15;
    float acc = 0.f;
    for (int j = q; j < cnt; j += 4)
        acc += ew[w][j] * h2[(size_t)colL[w][j] * NCLS + c];
    acc += __shfl_down(acc, 32, 64);
    acc += __shfl_down(acc, 16, 64);
    if (lane < NCLS)
        out[(size_t)i * NCLS + lane] = acc / sum + b2[lane];
}

extern "C" void kernel_launch(void* const* d_in, const int* in_sizes, int n_in,
                              void* d_out, int out_size, void* d_ws, size_t ws_size,
                              hipStream_t stream) {
    const float* x        = (const float*)d_in[0];
    const float* adj      = (const float*)d_in[1];
    const float* W1       = (const float*)d_in[2];
    const float* att_src1 = (const float*)d_in[3];
    const float* att_dst1 = (const float*)d_in[4];
    const float* b1       = (const float*)d_in[5];
    const float* W2       = (const float*)d_in[6];
    const float* att_src2 = (const float*)d_in[7];
    const float* att_dst2 = (const float*)d_in[8];
    const float* b2       = (const float*)d_in[9];
    float* out = (float*)d_out;

    char* ws = (char*)d_ws;
    int*    row_cnt = (int*)ws;     ws += (size_t)N_NODES * 4;
    int*    col_idx = (int*)ws;     ws += (size_t)N_NODES * CAP * 4;
    __half* h1f     = (__half*)ws;  ws += (size_t)N_NODES * HC * 2;
    float*  a_src   = (float*)ws;   ws += (size_t)N_NODES * H_HEADS * 4;
    float*  a_dst   = (float*)ws;   ws += (size_t)N_NODES * H_HEADS * 4;
    float*  h2      = (float*)ws;   ws += (size_t)N_NODES * NCLS * 4;
    float*  as2     = (float*)ws;   ws += (size_t)N_NODES * 4;
    float*  ad2     = (float*)ws;   ws += (size_t)N_NODES * 4;
    ushort* w_hiT   = (ushort*)ws;  ws += (size_t)F_IN * HC * 2;
    ushort* w_loT   = (ushort*)ws;  ws += (size_t)F_IN * HC * 2;

    hipLaunchKernelGGL(k_wsplit, dim3(64), dim3(256), 0, stream, W1, w_hiT, w_loT);
    hipLaunchKernelGGL(k_gemm1, dim3(GT + N_NODES), dim3(256), 0, stream,
                       x, w_hiT, w_loT, att_src1, att_dst1, adj,
                       h1f, a_src, a_dst, row_cnt, col_idx);
    hipLaunchKernelGGL(k_agg1, dim3(N_NODES), dim3(256), 0, stream,
                       h1f, a_src, a_dst, row_cnt, col_idx, b1,
                       W2, att_src2, att_dst2, h2, as2, ad2);
    hipLaunchKernelGGL(k_agg2, dim3(N_NODES / 4), dim3(256), 0, stream,
                       h2, as2, ad2, row_cnt, col_idx, b2, out);
}

// Round 6
// 152.887 us; speedup vs baseline: 1.0513x; 1.0513x over previous
//
#include <hip/hip_runtime.h>
#include <hip/hip_bf16.h>
#include <hip/hip_fp16.h>

#define N_NODES 4096
#define F_IN    512
#define HC      512   // H*C
#define H_HEADS 8
#define C_DIM   64
#define NCLS    16
#define CAP     192
#define NEG_SLOPE 0.2f

typedef __bf16 bf16x8 __attribute__((ext_vector_type(8)));
typedef float  f32x4  __attribute__((ext_vector_type(4)));
typedef unsigned short us8 __attribute__((ext_vector_type(8)));

// Staged operand layout: chunk(rg,kb) at ushort offset (rg*16+kb)*512; lane l
// holds 8 ushorts for row rg*16+(l&15), k = kb*32+(l>>4)*8.  global_load_lds
// stages chunk_base+lane*16B (coalesced) and the LDS image equals the MFMA
// fragment order -> conflict-free ds_read_b128.

#define XBLKS 1024   // 4096*512 elems / 8 per thread / 256 threads
#define WBLKS 64
#define GBLKS 512    // gemm1 tiles: b = head*64 + m  (XCD = b%8 = m%8 -> A-tile local to one XCD)

// ---------------- prep: split_x | split_wT (CSR lives in k_gemm1's grid) ----------------
__global__ __launch_bounds__(256) void k_split(const float* __restrict__ x,
                                               const float* __restrict__ W,
                                               ushort* __restrict__ xhi,
                                               ushort* __restrict__ xlo,
                                               ushort* __restrict__ whiT,
                                               ushort* __restrict__ wloT) {
    __shared__ float tile[64][65];
    int b = blockIdx.x;
    int t = threadIdx.x;
    if (b < XBLKS) {
        // ---- split x into bf16 hi/lo, staged layout ----
        int tid = b * 256 + t;
        int rg = tid >> 10;
        int c  = tid & 1023;
        int kb = c >> 6;
        int l  = c & 63;
        int row = rg * 16 + (l & 15);
        int kbase = kb * 32 + (l >> 4) * 8;
        const float* src = &x[(size_t)row * F_IN + kbase];
        float4 v0 = *(const float4*)&src[0];
        float4 v1 = *(const float4*)&src[4];
        float f[8] = {v0.x, v0.y, v0.z, v0.w, v1.x, v1.y, v1.z, v1.w};
        us8 hv, lv;
#pragma unroll
        for (int u = 0; u < 8; ++u) {
            __bf16 h = (__bf16)f[u];
            __bf16 lo_ = (__bf16)(f[u] - (float)h);
            hv[u] = __builtin_bit_cast(unsigned short, h);
            lv[u] = __builtin_bit_cast(unsigned short, lo_);
        }
        *(us8*)&xhi[(size_t)tid * 8] = hv;
        *(us8*)&xlo[(size_t)tid * 8] = lv;
    } else {
        // ---- split + transpose W1 -> staged layout ----
        int bb = b - XBLKS;
        int n0 = (bb & 7) * 64, k0 = (bb >> 3) * 64;
#pragma unroll
        for (int i = 0; i < 4; ++i) {
            int r = i * 16 + (t >> 4);
            int c = (t & 15) * 4;
            *(float4*)&tile[r][c] = *(const float4*)&W[(size_t)(k0 + r) * HC + n0 + c];
        }
        __syncthreads();
        int rg_local = t >> 6;
        int l = t & 63;
        int n_local = rg_local * 16 + (l & 15);
#pragma unroll
        for (int kb_local = 0; kb_local < 2; ++kb_local) {
            int k_local = kb_local * 32 + (l >> 4) * 8;
            us8 hv, lv;
#pragma unroll
            for (int u = 0; u < 8; ++u) {
                float f = tile[k_local + u][n_local];
                __bf16 h = (__bf16)f;
                __bf16 lo_ = (__bf16)(f - (float)h);
                hv[u] = __builtin_bit_cast(unsigned short, h);
                lv[u] = __builtin_bit_cast(unsigned short, lo_);
            }
            int rg = (n0 >> 4) + rg_local;
            int kb = (k0 >> 5) + kb_local;
            size_t off = ((size_t)(rg * 16 + kb) * 64 + l) * 8;
            *(us8*)&whiT[off] = hv;
            *(us8*)&wloT[off] = lv;
        }
    }
}

// ------- GEMM1 (bf16 MFMA 3-pass, all operands pre-staged) + attn scalars | CSR build -------
__global__ __launch_bounds__(256) void k_gemm1(const ushort* __restrict__ Ahi,
                                               const ushort* __restrict__ Alo,
                                               const ushort* __restrict__ Bhi,
                                               const ushort* __restrict__ Blo,
                                               const float* __restrict__ att_src,
                                               const float* __restrict__ att_dst,
                                               const float* __restrict__ adj,
                                               __half* __restrict__ C,
                                               float* __restrict__ a_src,
                                               float* __restrict__ a_dst,
                                               int* __restrict__ row_cnt,
                                               int* __restrict__ col_idx) {
    __shared__ __align__(16) ushort smem[4][2048];
    __shared__ float s_s[2][64], s_d[2][64];
    __shared__ int cnt_s;
    int b = blockIdx.x;
    int t = threadIdx.x;
    if (b >= GBLKS) {
        // ---- CSR build (adds self loop); pure HBM stream overlapping the GEMM ----
        int i = b - GBLKS;
        if (t == 0) cnt_s = 0;
        __syncthreads();
        const float4* row = (const float4*)(adj + (size_t)i * N_NODES);
        int* cols = col_idx + (size_t)i * CAP;
#pragma unroll
        for (int it = 0; it < 4; ++it) {
            int idx4 = it * 256 + t;
            float4 v = row[idx4];
            int j0 = idx4 * 4;
            if (v.x != 0.f && j0 + 0 != i) { int p = atomicAdd(&cnt_s, 1); if (p < CAP - 1) cols[p] = j0 + 0; }
            if (v.y != 0.f && j0 + 1 != i) { int p = atomicAdd(&cnt_s, 1); if (p < CAP - 1) cols[p] = j0 + 1; }
            if (v.z != 0.f && j0 + 2 != i) { int p = atomicAdd(&cnt_s, 1); if (p < CAP - 1) cols[p] = j0 + 2; }
            if (v.w != 0.f && j0 + 3 != i) { int p = atomicAdd(&cnt_s, 1); if (p < CAP - 1) cols[p] = j0 + 3; }
        }
        __syncthreads();
        if (t == 0) {
            int p = min(cnt_s, CAP - 1);
            cols[p] = i;
            row_cnt[i] = p + 1;
        }
        return;
    }
    int w = t >> 6, lane = t & 63;
    int head = b >> 6;                 // XCD = b%8 = m%8: all 8 heads of an m-tile on one XCD
    int n0 = head * 64;
    int m0 = (b & 63) * 64;
    const ushort* src = (w == 0) ? Ahi : (w == 1) ? Alo : (w == 2) ? Bhi : Blo;
    int rg0 = ((w < 2) ? m0 : n0) >> 4;
    int mw = (w & 1) * 32, nw = (w >> 1) * 32;
    f32x4 acc[2][2] = {};
    for (int kb = 0; kb < 16; ++kb) {
#pragma unroll
        for (int g = 0; g < 4; ++g) {
            const ushort* gp = src + ((size_t)((rg0 + g) * 16 + kb) * 64 + lane) * 8;
            __builtin_amdgcn_global_load_lds(
                (const __attribute__((address_space(1))) void*)gp,
                (__attribute__((address_space(3))) void*)&smem[w][g * 512],
                16, 0, 0);
        }
        __syncthreads();
        bf16x8 ahi[2], alo[2], bhi[2], blo[2];
#pragma unroll
        for (int mi = 0; mi < 2; ++mi) {
            int g = (mw >> 4) + mi;
            ahi[mi] = __builtin_bit_cast(bf16x8, *(const us8*)&smem[0][g * 512 + lane * 8]);
            alo[mi] = __builtin_bit_cast(bf16x8, *(const us8*)&smem[1][g * 512 + lane * 8]);
        }
#pragma unroll
        for (int ni = 0; ni < 2; ++ni) {
            int g = (nw >> 4) + ni;
            bhi[ni] = __builtin_bit_cast(bf16x8, *(const us8*)&smem[2][g * 512 + lane * 8]);
            blo[ni] = __builtin_bit_cast(bf16x8, *(const us8*)&smem[3][g * 512 + lane * 8]);
        }
#pragma unroll
        for (int mi = 0; mi < 2; ++mi)
#pragma unroll
            for (int ni = 0; ni < 2; ++ni) {
                acc[mi][ni] = __builtin_amdgcn_mfma_f32_16x16x32_bf16(ahi[mi], bhi[ni], acc[mi][ni], 0, 0, 0);
                acc[mi][ni] = __builtin_amdgcn_mfma_f32_16x16x32_bf16(alo[mi], bhi[ni], acc[mi][ni], 0, 0, 0);
                acc[mi][ni] = __builtin_amdgcn_mfma_f32_16x16x32_bf16(ahi[mi], blo[ni], acc[mi][ni], 0, 0, 0);
            }
        __syncthreads();
    }
    int r0 = (lane >> 4) * 4;
    int cn = lane & 15;
    // fused attention scalars: per-row dot with att vectors (fp32 accs)
    float as0 = att_src[n0 + nw + cn],      as1 = att_src[n0 + nw + 16 + cn];
    float ad0 = att_dst[n0 + nw + cn],      ad1 = att_dst[n0 + nw + 16 + cn];
#pragma unroll
    for (int mi = 0; mi < 2; ++mi)
#pragma unroll
        for (int r = 0; r < 4; ++r) {
            float ps = acc[mi][0][r] * as0 + acc[mi][1][r] * as1;
            float pd = acc[mi][0][r] * ad0 + acc[mi][1][r] * ad1;
#pragma unroll
            for (int o = 1; o < 16; o <<= 1) {
                ps += __shfl_xor(ps, o, 64);
                pd += __shfl_xor(pd, o, 64);
            }
            if (cn == 0) {
                int row = mw + mi * 16 + r0 + r;
                s_s[w >> 1][row] = ps;
                s_d[w >> 1][row] = pd;
            }
        }
    // C store (fp16)
#pragma unroll
    for (int mi = 0; mi < 2; ++mi)
#pragma unroll
        for (int ni = 0; ni < 2; ++ni) {
            size_t base = (size_t)(m0 + mw + mi * 16 + r0) * HC + (n0 + nw + ni * 16 + cn);
#pragma unroll
            for (int r = 0; r < 4; ++r)
                C[base + (size_t)r * HC] = __float2half(acc[mi][ni][r]);
        }
    __syncthreads();
    if (t < 64) {
        a_src[(m0 + t) * H_HEADS + head] = s_s[0][t] + s_s[1][t];
        a_dst[(m0 + t) * H_HEADS + head] = s_d[0][t] + s_d[1][t];
    }
}

// ------- layer-1 softmax aggregation + bias + ELU + fused GEMM2 + layer-2 scalars -------
__global__ __launch_bounds__(256) void k_agg1(const __half* __restrict__ hf,
                                              const float* __restrict__ a_src,
                                              const float* __restrict__ a_dst,
                                              const int* __restrict__ row_cnt,
                                              const int* __restrict__ col_idx,
                                              const float* __restrict__ b1,
                                              const float* __restrict__ W2,       // [512,16]
                                              const float* __restrict__ att_src2, // [16]
                                              const float* __restrict__ att_dst2, // [16]
                                              float* __restrict__ h2,
                                              float* __restrict__ a_src2,
                                              float* __restrict__ a_dst2) {
    int i = blockIdx.x;
    int t = threadIdx.x;
    __shared__ float wL[CAP][H_HEADS];
    __shared__ int   colL[CAP];
    __shared__ float denom[H_HEADS];
    __shared__ float ad[H_HEADS];
    __shared__ float elu_s[HC];
    __shared__ float part[16][17];
    int cnt = row_cnt[i];
    if (t < H_HEADS) ad[t] = a_dst[i * H_HEADS + t];
    for (int j = t; j < cnt; j += 256) colL[j] = col_idx[(size_t)i * CAP + j];
    __syncthreads();
    for (int idx = t; idx < cnt * H_HEADS; idx += 256) {
        int j = idx >> 3, h = idx & 7;
        float l = a_src[colL[j] * H_HEADS + h] + ad[h];
        l = (l > 0.f) ? l : NEG_SLOPE * l;
        wL[j][h] = __expf(l);
    }
    __syncthreads();
    {
        int h = t >> 5, l32 = t & 31;
        float s = 0.f;
        for (int j = l32; j < cnt; j += 32) s += wL[j][h];
#pragma unroll
        for (int o = 16; o > 0; o >>= 1) s += __shfl_down(s, o, 32);
        if (l32 == 0) denom[h] = s;
    }
    __syncthreads();
    int e = t * 2;
    int h = e >> 6;
    float ax = 0.f, ay = 0.f;
    int j = 0;
    for (; j + 8 <= cnt; j += 8) {
        int c0 = colL[j],     c1 = colL[j + 1], c2 = colL[j + 2], c3 = colL[j + 3];
        int c4 = colL[j + 4], c5 = colL[j + 5], c6 = colL[j + 6], c7 = colL[j + 7];
        float2 v0 = __half22float2(*(const __half2*)&hf[(size_t)c0 * HC + e]);
        float2 v1 = __half22float2(*(const __half2*)&hf[(size_t)c1 * HC + e]);
        float2 v2 = __half22float2(*(const __half2*)&hf[(size_t)c2 * HC + e]);
        float2 v3 = __half22float2(*(const __half2*)&hf[(size_t)c3 * HC + e]);
        float2 v4 = __half22float2(*(const __half2*)&hf[(size_t)c4 * HC + e]);
        float2 v5 = __half22float2(*(const __half2*)&hf[(size_t)c5 * HC + e]);
        float2 v6 = __half22float2(*(const __half2*)&hf[(size_t)c6 * HC + e]);
        float2 v7 = __half22float2(*(const __half2*)&hf[(size_t)c7 * HC + e]);
        float w0 = wL[j][h],     w1 = wL[j + 1][h], w2 = wL[j + 2][h], w3 = wL[j + 3][h];
        float w4 = wL[j + 4][h], w5 = wL[j + 5][h], w6 = wL[j + 6][h], w7 = wL[j + 7][h];
        ax += w0 * v0.x + w1 * v1.x + w2 * v2.x + w3 * v3.x
            + w4 * v4.x + w5 * v5.x + w6 * v6.x + w7 * v7.x;
        ay += w0 * v0.y + w1 * v1.y + w2 * v2.y + w3 * v3.y
            + w4 * v4.y + w5 * v5.y + w6 * v6.y + w7 * v7.y;
    }
    for (; j + 4 <= cnt; j += 4) {
        int c0 = colL[j], c1 = colL[j + 1], c2 = colL[j + 2], c3 = colL[j + 3];
        float2 v0 = __half22float2(*(const __half2*)&hf[(size_t)c0 * HC + e]);
        float2 v1 = __half22float2(*(const __half2*)&hf[(size_t)c1 * HC + e]);
        float2 v2 = __half22float2(*(const __half2*)&hf[(size_t)c2 * HC + e]);
        float2 v3 = __half22float2(*(const __half2*)&hf[(size_t)c3 * HC + e]);
        float w0 = wL[j][h], w1 = wL[j + 1][h], w2 = wL[j + 2][h], w3 = wL[j + 3][h];
        ax += w0 * v0.x + w1 * v1.x + w2 * v2.x + w3 * v3.x;
        ay += w0 * v0.y + w1 * v1.y + w2 * v2.y + w3 * v3.y;
    }
    for (; j < cnt; ++j) {
        int c0 = colL[j];
        float2 v0 = __half22float2(*(const __half2*)&hf[(size_t)c0 * HC + e]);
        float w0 = wL[j][h];
        ax += w0 * v0.x;
        ay += w0 * v0.y;
    }
    float inv = 1.f / denom[h];
    float o0 = ax * inv + b1[e];
    float o1 = ay * inv + b1[e + 1];
    o0 = (o0 > 0.f) ? o0 : (__expf(o0) - 1.f);
    o1 = (o1 > 0.f) ? o1 : (__expf(o1) - 1.f);
    elu_s[e]     = o0;
    elu_s[e + 1] = o1;
    __syncthreads();
    // ---- fused GEMM2: h2[i,:] = elu_row @ W2  (512x16) ----
    int kg = t >> 4, c = t & 15;
    float p = 0.f;
    const float* w2p = W2 + (size_t)kg * 32 * NCLS + c;
    const float* es  = &elu_s[kg * 32];
#pragma unroll 8
    for (int kk = 0; kk < 32; ++kk) p += es[kk] * w2p[kk * NCLS];
    part[kg][c] = p;
    __syncthreads();
    if (t < 16) {
        float s = 0.f;
#pragma unroll
        for (int r = 0; r < 16; ++r) s += part[r][t];
        h2[(size_t)i * NCLS + t] = s;
        float vs = s * att_src2[t], vd = s * att_dst2[t];
#pragma unroll
        for (int o = 8; o > 0; o >>= 1) {
            vs += __shfl_xor(vs, o, 64);
            vd += __shfl_xor(vd, o, 64);
        }
        if (t == 0) { a_src2[i] = vs; a_dst2[i] = vd; }
    }
}

// ---------------- layer-2 softmax aggregation ----------------
__global__ __launch_bounds__(256) void k_agg2(const float* __restrict__ h2,
                                              const float* __restrict__ a_src2,
                                              const float* __restrict__ a_dst2,
                                              const int* __restrict__ row_cnt,
                                              const int* __restrict__ col_idx,
                                              const float* __restrict__ b2,
                                              float* __restrict__ out) {
    int t = threadIdx.x;
    int w = t >> 6, lane = t & 63;
    int i = blockIdx.x * 4 + w;
    __shared__ float ew[4][CAP];
    __shared__ int   colL[4][CAP];
    int cnt = row_cnt[i];
    float adi = a_dst2[i];
    float sum = 0.f;
    for (int j = lane; j < cnt; j += 64) {
        int col = col_idx[(size_t)i * CAP + j];
        colL[w][j] = col;
        float l = a_src2[col] + adi;
        l = (l > 0.f) ? l : NEG_SLOPE * l;
        float e = __expf(l);
        ew[w][j] = e;
        sum += e;
    }
#pragma unroll
    for (int o = 32; o > 0; o >>= 1) sum += __shfl_xor(sum, o, 64);
    int q = lane >> 4, c = lane & 15;
    float acc = 0.f;
    for (int j = q; j < cnt; j += 4)
        acc += ew[w][j] * h2[(size_t)colL[w][j] * NCLS + c];
    acc += __shfl_down(acc, 32, 64);
    acc += __shfl_down(acc, 16, 64);
    if (lane < NCLS)
        out[(size_t)i * NCLS + lane] = acc / sum + b2[lane];
}

extern "C" void kernel_launch(void* const* d_in, const int* in_sizes, int n_in,
                              void* d_out, int out_size, void* d_ws, size_t ws_size,
                              hipStream_t stream) {
    const float* x        = (const float*)d_in[0];
    const float* adj      = (const float*)d_in[1];
    const float* W1       = (const float*)d_in[2];
    const float* att_src1 = (const float*)d_in[3];
    const float* att_dst1 = (const float*)d_in[4];
    const float* b1       = (const float*)d_in[5];
    const float* W2       = (const float*)d_in[6];
    const float* att_src2 = (const float*)d_in[7];
    const float* att_dst2 = (const float*)d_in[8];
    const float* b2       = (const float*)d_in[9];
    float* out = (float*)d_out;

    char* ws = (char*)d_ws;
    int*    row_cnt = (int*)ws;     ws += (size_t)N_NODES * 4;
    int*    col_idx = (int*)ws;     ws += (size_t)N_NODES * CAP * 4;
    __half* h1f     = (__half*)ws;  ws += (size_t)N_NODES * HC * 2;
    float*  a_src   = (float*)ws;   ws += (size_t)N_NODES * H_HEADS * 4;
    float*  a_dst   = (float*)ws;   ws += (size_t)N_NODES * H_HEADS * 4;
    float*  h2      = (float*)ws;   ws += (size_t)N_NODES * NCLS * 4;
    float*  as2     = (float*)ws;   ws += (size_t)N_NODES * 4;
    float*  ad2     = (float*)ws;   ws += (size_t)N_NODES * 4;
    ushort* x_hi    = (ushort*)ws;  ws += (size_t)N_NODES * F_IN * 2;
    ushort* x_lo    = (ushort*)ws;  ws += (size_t)N_NODES * F_IN * 2;
    ushort* w_hiT   = (ushort*)ws;  ws += (size_t)F_IN * HC * 2;
    ushort* w_loT   = (ushort*)ws;  ws += (size_t)F_IN * HC * 2;

    hipLaunchKernelGGL(k_split, dim3(XBLKS + WBLKS), dim3(256), 0, stream,
                       x, W1, x_hi, x_lo, w_hiT, w_loT);
    hipLaunchKernelGGL(k_gemm1, dim3(GBLKS + N_NODES), dim3(256), 0, stream,
                       x_hi, x_lo, w_hiT, w_loT, att_src1, att_dst1, adj,
                       h1f, a_src, a_dst, row_cnt, col_idx);
    hipLaunchKernelGGL(k_agg1, dim3(N_NODES), dim3(256), 0, stream,
                       h1f, a_src, a_dst, row_cnt, col_idx, b1,
                       W2, att_src2, att_dst2, h2, as2, ad2);
    hipLaunchKernelGGL(k_agg2, dim3(N_NODES / 4), dim3(256), 0, stream,
                       h2, as2, ad2, row_cnt, col_idx, b2, out);
}

// Round 7
// 149.895 us; speedup vs baseline: 1.0723x; 1.0200x over previous
//
#include <hip/hip_runtime.h>
#include <hip/hip_bf16.h>
#include <hip/hip_fp16.h>

#define N_NODES 4096
#define F_IN    512
#define HC      512   // H*C
#define H_HEADS 8
#define C_DIM   64
#define NCLS    16
#define CAP     192
#define NEG_SLOPE 0.2f

typedef __bf16 bf16x8 __attribute__((ext_vector_type(8)));
typedef float  f32x4  __attribute__((ext_vector_type(4)));
typedef unsigned short us8 __attribute__((ext_vector_type(8)));

// Staged operand layout: chunk(rg,kb) at ushort offset (rg*16+kb)*512; lane l
// holds 8 ushorts for row rg*16+(l&15), k = kb*32+(l>>4)*8.  global_load_lds
// stages chunk_base+lane*16B (coalesced) and the LDS image equals the MFMA
// fragment order -> conflict-free ds_read_b128.

#define XBLKS 1024   // 4096*512 elems / 8 per thread / 256 threads
#define WBLKS 64
#define GBLKS 512    // gemm1 tiles: b = head*64 + m  (XCD = b%8 = m%8 -> A-tile local to one XCD)

// ---------------- prep: split_x | split_wT (CSR lives in k_gemm1's grid) ----------------
__global__ __launch_bounds__(256) void k_split(const float* __restrict__ x,
                                               const float* __restrict__ W,
                                               ushort* __restrict__ xhi,
                                               ushort* __restrict__ xlo,
                                               ushort* __restrict__ whiT,
                                               ushort* __restrict__ wloT) {
    __shared__ float tile[64][65];
    int b = blockIdx.x;
    int t = threadIdx.x;
    if (b < XBLKS) {
        // ---- split x into bf16 hi/lo, staged layout ----
        int tid = b * 256 + t;
        int rg = tid >> 10;
        int c  = tid & 1023;
        int kb = c >> 6;
        int l  = c & 63;
        int row = rg * 16 + (l & 15);
        int kbase = kb * 32 + (l >> 4) * 8;
        const float* src = &x[(size_t)row * F_IN + kbase];
        float4 v0 = *(const float4*)&src[0];
        float4 v1 = *(const float4*)&src[4];
        float f[8] = {v0.x, v0.y, v0.z, v0.w, v1.x, v1.y, v1.z, v1.w};
        us8 hv, lv;
#pragma unroll
        for (int u = 0; u < 8; ++u) {
            __bf16 h = (__bf16)f[u];
            __bf16 lo_ = (__bf16)(f[u] - (float)h);
            hv[u] = __builtin_bit_cast(unsigned short, h);
            lv[u] = __builtin_bit_cast(unsigned short, lo_);
        }
        *(us8*)&xhi[(size_t)tid * 8] = hv;
        *(us8*)&xlo[(size_t)tid * 8] = lv;
    } else {
        // ---- split + transpose W1 -> staged layout ----
        int bb = b - XBLKS;
        int n0 = (bb & 7) * 64, k0 = (bb >> 3) * 64;
#pragma unroll
        for (int i = 0; i < 4; ++i) {
            int r = i * 16 + (t >> 4);
            int c = (t & 15) * 4;
            *(float4*)&tile[r][c] = *(const float4*)&W[(size_t)(k0 + r) * HC + n0 + c];
        }
        __syncthreads();
        int rg_local = t >> 6;
        int l = t & 63;
        int n_local = rg_local * 16 + (l & 15);
#pragma unroll
        for (int kb_local = 0; kb_local < 2; ++kb_local) {
            int k_local = kb_local * 32 + (l >> 4) * 8;
            us8 hv, lv;
#pragma unroll
            for (int u = 0; u < 8; ++u) {
                float f = tile[k_local + u][n_local];
                __bf16 h = (__bf16)f;
                __bf16 lo_ = (__bf16)(f - (float)h);
                hv[u] = __builtin_bit_cast(unsigned short, h);
                lv[u] = __builtin_bit_cast(unsigned short, lo_);
            }
            int rg = (n0 >> 4) + rg_local;
            int kb = (k0 >> 5) + kb_local;
            size_t off = ((size_t)(rg * 16 + kb) * 64 + l) * 8;
            *(us8*)&whiT[off] = hv;
            *(us8*)&wloT[off] = lv;
        }
    }
}

// ------- GEMM1 (bf16 MFMA 3-pass, all operands pre-staged) + attn scalars | CSR build -------
__global__ __launch_bounds__(256) void k_gemm1(const ushort* __restrict__ Ahi,
                                               const ushort* __restrict__ Alo,
                                               const ushort* __restrict__ Bhi,
                                               const ushort* __restrict__ Blo,
                                               const float* __restrict__ att_src,
                                               const float* __restrict__ att_dst,
                                               const float* __restrict__ adj,
                                               __half* __restrict__ C,
                                               float* __restrict__ a_src,
                                               float* __restrict__ a_dst,
                                               int* __restrict__ row_cnt,
                                               int* __restrict__ col_idx) {
    __shared__ __align__(16) ushort smem[4][2048];
    __shared__ float s_s[2][64], s_d[2][64];
    __shared__ int cnt_s;
    int b = blockIdx.x;
    int t = threadIdx.x;
    if (b >= GBLKS) {
        // ---- CSR build (adds self loop); pure HBM stream overlapping the GEMM ----
        int i = b - GBLKS;
        if (t == 0) cnt_s = 0;
        __syncthreads();
        const float4* row = (const float4*)(adj + (size_t)i * N_NODES);
        int* cols = col_idx + (size_t)i * CAP;
#pragma unroll
        for (int it = 0; it < 4; ++it) {
            int idx4 = it * 256 + t;
            float4 v = row[idx4];
            int j0 = idx4 * 4;
            if (v.x != 0.f && j0 + 0 != i) { int p = atomicAdd(&cnt_s, 1); if (p < CAP - 1) cols[p] = j0 + 0; }
            if (v.y != 0.f && j0 + 1 != i) { int p = atomicAdd(&cnt_s, 1); if (p < CAP - 1) cols[p] = j0 + 1; }
            if (v.z != 0.f && j0 + 2 != i) { int p = atomicAdd(&cnt_s, 1); if (p < CAP - 1) cols[p] = j0 + 2; }
            if (v.w != 0.f && j0 + 3 != i) { int p = atomicAdd(&cnt_s, 1); if (p < CAP - 1) cols[p] = j0 + 3; }
        }
        __syncthreads();
        if (t == 0) {
            int p = min(cnt_s, CAP - 1);
            cols[p] = i;
            row_cnt[i] = p + 1;
        }
        return;
    }
    int w = t >> 6, lane = t & 63;
    int head = b >> 6;                 // XCD = b%8 = m%8: all 8 heads of an m-tile on one XCD
    int n0 = head * 64;
    int m0 = (b & 63) * 64;
    const ushort* src = (w == 0) ? Ahi : (w == 1) ? Alo : (w == 2) ? Bhi : Blo;
    int rg0 = ((w < 2) ? m0 : n0) >> 4;
    int mw = (w & 1) * 32, nw = (w >> 1) * 32;
    f32x4 acc[2][2] = {};
    for (int kb = 0; kb < 16; ++kb) {
#pragma unroll
        for (int g = 0; g < 4; ++g) {
            const ushort* gp = src + ((size_t)((rg0 + g) * 16 + kb) * 64 + lane) * 8;
            __builtin_amdgcn_global_load_lds(
                (const __attribute__((address_space(1))) void*)gp,
                (__attribute__((address_space(3))) void*)&smem[w][g * 512],
                16, 0, 0);
        }
        __syncthreads();
        bf16x8 ahi[2], alo[2], bhi[2], blo[2];
#pragma unroll
        for (int mi = 0; mi < 2; ++mi) {
            int g = (mw >> 4) + mi;
            ahi[mi] = __builtin_bit_cast(bf16x8, *(const us8*)&smem[0][g * 512 + lane * 8]);
            alo[mi] = __builtin_bit_cast(bf16x8, *(const us8*)&smem[1][g * 512 + lane * 8]);
        }
#pragma unroll
        for (int ni = 0; ni < 2; ++ni) {
            int g = (nw >> 4) + ni;
            bhi[ni] = __builtin_bit_cast(bf16x8, *(const us8*)&smem[2][g * 512 + lane * 8]);
            blo[ni] = __builtin_bit_cast(bf16x8, *(const us8*)&smem[3][g * 512 + lane * 8]);
        }
#pragma unroll
        for (int mi = 0; mi < 2; ++mi)
#pragma unroll
            for (int ni = 0; ni < 2; ++ni) {
                acc[mi][ni] = __builtin_amdgcn_mfma_f32_16x16x32_bf16(ahi[mi], bhi[ni], acc[mi][ni], 0, 0, 0);
                acc[mi][ni] = __builtin_amdgcn_mfma_f32_16x16x32_bf16(alo[mi], bhi[ni], acc[mi][ni], 0, 0, 0);
                acc[mi][ni] = __builtin_amdgcn_mfma_f32_16x16x32_bf16(ahi[mi], blo[ni], acc[mi][ni], 0, 0, 0);
            }
        __syncthreads();
    }
    int r0 = (lane >> 4) * 4;
    int cn = lane & 15;
    // fused attention scalars: per-row dot with att vectors (fp32 accs)
    float as0 = att_src[n0 + nw + cn],      as1 = att_src[n0 + nw + 16 + cn];
    float ad0 = att_dst[n0 + nw + cn],      ad1 = att_dst[n0 + nw + 16 + cn];
#pragma unroll
    for (int mi = 0; mi < 2; ++mi)
#pragma unroll
        for (int r = 0; r < 4; ++r) {
            float ps = acc[mi][0][r] * as0 + acc[mi][1][r] * as1;
            float pd = acc[mi][0][r] * ad0 + acc[mi][1][r] * ad1;
#pragma unroll
            for (int o = 1; o < 16; o <<= 1) {
                ps += __shfl_xor(ps, o, 64);
                pd += __shfl_xor(pd, o, 64);
            }
            if (cn == 0) {
                int row = mw + mi * 16 + r0 + r;
                s_s[w >> 1][row] = ps;
                s_d[w >> 1][row] = pd;
            }
        }
    // C store (fp16)
#pragma unroll
    for (int mi = 0; mi < 2; ++mi)
#pragma unroll
        for (int ni = 0; ni < 2; ++ni) {
            size_t base = (size_t)(m0 + mw + mi * 16 + r0) * HC + (n0 + nw + ni * 16 + cn);
#pragma unroll
            for (int r = 0; r < 4; ++r)
                C[base + (size_t)r * HC] = __float2half(acc[mi][ni][r]);
        }
    __syncthreads();
    if (t < 64) {
        a_src[(m0 + t) * H_HEADS + head] = s_s[0][t] + s_s[1][t];
        a_dst[(m0 + t) * H_HEADS + head] = s_d[0][t] + s_d[1][t];
    }
}

// ------- layer-1 softmax aggregation + bias + ELU + fused GEMM2 + layer-2 scalars -------
// 2 rows per block, 128 threads/row, 4 halfs (8B dwordx2) per thread per neighbor.
__global__ __launch_bounds__(256) void k_agg1(const __half* __restrict__ hf,
                                              const float* __restrict__ a_src,
                                              const float* __restrict__ a_dst,
                                              const int* __restrict__ row_cnt,
                                              const int* __restrict__ col_idx,
                                              const float* __restrict__ b1,
                                              const float* __restrict__ W2,       // [512,16]
                                              const float* __restrict__ att_src2, // [16]
                                              const float* __restrict__ att_dst2, // [16]
                                              float* __restrict__ h2,
                                              float* __restrict__ a_src2,
                                              float* __restrict__ a_dst2) {
    int t = threadIdx.x;
    int r = t >> 7;            // row slot within block
    int tt = t & 127;
    int i = blockIdx.x * 2 + r;
    __shared__ float wL[2][CAP][H_HEADS];   // 12 KB
    __shared__ int   colL[2][CAP];
    __shared__ float denom[2][H_HEADS];
    __shared__ float ad[2][H_HEADS];
    __shared__ float elu_s[2][HC];          // 4 KB
    __shared__ float part[2][8][17];
    int cnt = row_cnt[i];
    if (tt < H_HEADS) ad[r][tt] = a_dst[i * H_HEADS + tt];
    for (int j = tt; j < cnt; j += 128) colL[r][j] = col_idx[(size_t)i * CAP + j];
    __syncthreads();
    for (int idx = tt; idx < cnt * H_HEADS; idx += 128) {
        int j = idx >> 3, h = idx & 7;
        float l = a_src[colL[r][j] * H_HEADS + h] + ad[r][h];
        l = (l > 0.f) ? l : NEG_SLOPE * l;
        wL[r][j][h] = __expf(l);
    }
    __syncthreads();
    {
        int h = tt >> 4, l16 = tt & 15;     // 16 threads per head
        float s = 0.f;
        for (int j = l16; j < cnt; j += 16) s += wL[r][j][h];
#pragma unroll
        for (int o = 8; o > 0; o >>= 1) s += __shfl_down(s, o, 16);
        if (l16 == 0) denom[r][h] = s;
    }
    __syncthreads();
    int e = tt * 4;            // 4 consecutive halfs per thread
    int h = tt >> 4;           // head = e>>6
    float a0 = 0.f, a1 = 0.f, a2 = 0.f, a3 = 0.f;
    int j = 0;
    for (; j + 8 <= cnt; j += 8) {
#pragma unroll
        for (int u = 0; u < 8; ++u) {
            int c = colL[r][j + u];
            uint2 q = *(const uint2*)&hf[(size_t)c * HC + e];
            float2 f01 = __half22float2(__builtin_bit_cast(__half2, q.x));
            float2 f23 = __half22float2(__builtin_bit_cast(__half2, q.y));
            float wj = wL[r][j + u][h];
            a0 += wj * f01.x; a1 += wj * f01.y;
            a2 += wj * f23.x; a3 += wj * f23.y;
        }
    }
    for (; j < cnt; ++j) {
        int c = colL[r][j];
        uint2 q = *(const uint2*)&hf[(size_t)c * HC + e];
        float2 f01 = __half22float2(__builtin_bit_cast(__half2, q.x));
        float2 f23 = __half22float2(__builtin_bit_cast(__half2, q.y));
        float wj = wL[r][j][h];
        a0 += wj * f01.x; a1 += wj * f01.y;
        a2 += wj * f23.x; a3 += wj * f23.y;
    }
    float inv = 1.f / denom[r][h];
    float o0 = a0 * inv + b1[e];
    float o1 = a1 * inv + b1[e + 1];
    float o2 = a2 * inv + b1[e + 2];
    float o3 = a3 * inv + b1[e + 3];
    o0 = (o0 > 0.f) ? o0 : (__expf(o0) - 1.f);
    o1 = (o1 > 0.f) ? o1 : (__expf(o1) - 1.f);
    o2 = (o2 > 0.f) ? o2 : (__expf(o2) - 1.f);
    o3 = (o3 > 0.f) ? o3 : (__expf(o3) - 1.f);
    elu_s[r][e]     = o0;
    elu_s[r][e + 1] = o1;
    elu_s[r][e + 2] = o2;
    elu_s[r][e + 3] = o3;
    __syncthreads();
    // ---- fused GEMM2: h2[i,:] = elu_row @ W2  (512x16); 128 thr/row: kg 0..7 x c 0..15 ----
    {
        int kg = tt >> 4, c = tt & 15;
        float p = 0.f;
        const float* w2p = W2 + (size_t)kg * 64 * NCLS + c;
        const float* es  = &elu_s[r][kg * 64];
#pragma unroll 8
        for (int kk = 0; kk < 64; ++kk) p += es[kk] * w2p[kk * NCLS];
        part[r][kg][c] = p;
    }
    __syncthreads();
    if (tt < 16) {
        float s = 0.f;
#pragma unroll
        for (int g = 0; g < 8; ++g) s += part[r][g][tt];
        h2[(size_t)i * NCLS + tt] = s;
        float vs = s * att_src2[tt], vd = s * att_dst2[tt];
#pragma unroll
        for (int o = 8; o > 0; o >>= 1) {
            vs += __shfl_xor(vs, o, 16);
            vd += __shfl_xor(vd, o, 16);
        }
        if (tt == 0) { a_src2[i] = vs; a_dst2[i] = vd; }
    }
}

// ---------------- layer-2 softmax aggregation ----------------
__global__ __launch_bounds__(256) void k_agg2(const float* __restrict__ h2,
                                              const float* __restrict__ a_src2,
                                              const float* __restrict__ a_dst2,
                                              const int* __restrict__ row_cnt,
                                              const int* __restrict__ col_idx,
                                              const float* __restrict__ b2,
                                              float* __restrict__ out) {
    int t = threadIdx.x;
    int w = t >> 6, lane = t & 63;
    int i = blockIdx.x * 4 + w;
    __shared__ float ew[4][CAP];
    __shared__ int   colL[4][CAP];
    int cnt = row_cnt[i];
    float adi = a_dst2[i];
    float sum = 0.f;
    for (int j = lane; j < cnt; j += 64) {
        int col = col_idx[(size_t)i * CAP + j];
        colL[w][j] = col;
        float l = a_src2[col] + adi;
        l = (l > 0.f) ? l : NEG_SLOPE * l;
        float e = __expf(l);
        ew[w][j] = e;
        sum += e;
    }
#pragma unroll
    for (int o = 32; o > 0; o >>= 1) sum += __shfl_xor(sum, o, 64);
    int q = lane >> 4, c = lane & 15;
    float acc = 0.f;
    for (int j = q; j < cnt; j += 4)
        acc += ew[w][j] * h2[(size_t)colL[w][j] * NCLS + c];
    acc += __shfl_down(acc, 32, 64);
    acc += __shfl_down(acc, 16, 64);
    if (lane < NCLS)
        out[(size_t)i * NCLS + lane] = acc / sum + b2[lane];
}

extern "C" void kernel_launch(void* const* d_in, const int* in_sizes, int n_in,
                              void* d_out, int out_size, void* d_ws, size_t ws_size,
                              hipStream_t stream) {
    const float* x        = (const float*)d_in[0];
    const float* adj      = (const float*)d_in[1];
    const float* W1       = (const float*)d_in[2];
    const float* att_src1 = (const float*)d_in[3];
    const float* att_dst1 = (const float*)d_in[4];
    const float* b1       = (const float*)d_in[5];
    const float* W2       = (const float*)d_in[6];
    const float* att_src2 = (const float*)d_in[7];
    const float* att_dst2 = (const float*)d_in[8];
    const float* b2       = (const float*)d_in[9];
    float* out = (float*)d_out;

    char* ws = (char*)d_ws;
    int*    row_cnt = (int*)ws;     ws += (size_t)N_NODES * 4;
    int*    col_idx = (int*)ws;     ws += (size_t)N_NODES * CAP * 4;
    __half* h1f     = (__half*)ws;  ws += (size_t)N_NODES * HC * 2;
    float*  a_src   = (float*)ws;   ws += (size_t)N_NODES * H_HEADS * 4;
    float*  a_dst   = (float*)ws;   ws += (size_t)N_NODES * H_HEADS * 4;
    float*  h2      = (float*)ws;   ws += (size_t)N_NODES * NCLS * 4;
    float*  as2     = (float*)ws;   ws += (size_t)N_NODES * 4;
    float*  ad2     = (float*)ws;   ws += (size_t)N_NODES * 4;
    ushort* x_hi    = (ushort*)ws;  ws += (size_t)N_NODES * F_IN * 2;
    ushort* x_lo    = (ushort*)ws;  ws += (size_t)N_NODES * F_IN * 2;
    ushort* w_hiT   = (ushort*)ws;  ws += (size_t)F_IN * HC * 2;
    ushort* w_loT   = (ushort*)ws;  ws += (size_t)F_IN * HC * 2;

    hipLaunchKernelGGL(k_split, dim3(XBLKS + WBLKS), dim3(256), 0, stream,
                       x, W1, x_hi, x_lo, w_hiT, w_loT);
    hipLaunchKernelGGL(k_gemm1, dim3(GBLKS + N_NODES), dim3(256), 0, stream,
                       x_hi, x_lo, w_hiT, w_loT, att_src1, att_dst1, adj,
                       h1f, a_src, a_dst, row_cnt, col_idx);
    hipLaunchKernelGGL(k_agg1, dim3(N_NODES / 2), dim3(256), 0, stream,
                       h1f, a_src, a_dst, row_cnt, col_idx, b1,
                       W2, att_src2, att_dst2, h2, as2, ad2);
    hipLaunchKernelGGL(k_agg2, dim3(N_NODES / 4), dim3(256), 0, stream,
                       h2, as2, ad2, row_cnt, col_idx, b2, out);
}

// Round 8
// 148.059 us; speedup vs baseline: 1.0855x; 1.0124x over previous
//
#include <hip/hip_runtime.h>
#include <hip/hip_bf16.h>
#include <hip/hip_fp16.h>

#define N_NODES 4096
#define F_IN    512
#define HC      512   // H*C
#define H_HEADS 8
#define C_DIM   64
#define NCLS    16
#define CAP     192
#define NEG_SLOPE 0.2f

typedef __bf16 bf16x8 __attribute__((ext_vector_type(8)));
typedef float  f32x4  __attribute__((ext_vector_type(4)));
typedef unsigned short us8 __attribute__((ext_vector_type(8)));

// Staged operand layout: chunk(rg,kb) at ushort offset (rg*16+kb)*512; lane l
// holds 8 ushorts for row rg*16+(l&15), k = kb*32+(l>>4)*8.  global_load_lds
// stages chunk_base+lane*16B (coalesced) and the LDS image equals the MFMA
// fragment order -> conflict-free ds_read_b128.

#define XBLKS 1024   // 4096*512 elems / 8 per thread / 256 threads
#define WBLKS 64
#define GBLKS 512    // gemm1 tiles: b = head*64 + m  (XCD = b%8 = m%8 -> A-tile local to one XCD)

// ---------------- prep: split_x | split_wT (CSR lives in k_gemm1's grid) ----------------
__global__ __launch_bounds__(256) void k_split(const float* __restrict__ x,
                                               const float* __restrict__ W,
                                               ushort* __restrict__ xhi,
                                               ushort* __restrict__ xlo,
                                               ushort* __restrict__ whiT,
                                               ushort* __restrict__ wloT) {
    __shared__ float tile[64][65];
    int b = blockIdx.x;
    int t = threadIdx.x;
    if (b < XBLKS) {
        // ---- split x into bf16 hi/lo, staged layout ----
        int tid = b * 256 + t;
        int rg = tid >> 10;
        int c  = tid & 1023;
        int kb = c >> 6;
        int l  = c & 63;
        int row = rg * 16 + (l & 15);
        int kbase = kb * 32 + (l >> 4) * 8;
        const float* src = &x[(size_t)row * F_IN + kbase];
        float4 v0 = *(const float4*)&src[0];
        float4 v1 = *(const float4*)&src[4];
        float f[8] = {v0.x, v0.y, v0.z, v0.w, v1.x, v1.y, v1.z, v1.w};
        us8 hv, lv;
#pragma unroll
        for (int u = 0; u < 8; ++u) {
            __bf16 h = (__bf16)f[u];
            __bf16 lo_ = (__bf16)(f[u] - (float)h);
            hv[u] = __builtin_bit_cast(unsigned short, h);
            lv[u] = __builtin_bit_cast(unsigned short, lo_);
        }
        *(us8*)&xhi[(size_t)tid * 8] = hv;
        *(us8*)&xlo[(size_t)tid * 8] = lv;
    } else {
        // ---- split + transpose W1 -> staged layout ----
        int bb = b - XBLKS;
        int n0 = (bb & 7) * 64, k0 = (bb >> 3) * 64;
#pragma unroll
        for (int i = 0; i < 4; ++i) {
            int r = i * 16 + (t >> 4);
            int c = (t & 15) * 4;
            *(float4*)&tile[r][c] = *(const float4*)&W[(size_t)(k0 + r) * HC + n0 + c];
        }
        __syncthreads();
        int rg_local = t >> 6;
        int l = t & 63;
        int n_local = rg_local * 16 + (l & 15);
#pragma unroll
        for (int kb_local = 0; kb_local < 2; ++kb_local) {
            int k_local = kb_local * 32 + (l >> 4) * 8;
            us8 hv, lv;
#pragma unroll
            for (int u = 0; u < 8; ++u) {
                float f = tile[k_local + u][n_local];
                __bf16 h = (__bf16)f;
                __bf16 lo_ = (__bf16)(f - (float)h);
                hv[u] = __builtin_bit_cast(unsigned short, h);
                lv[u] = __builtin_bit_cast(unsigned short, lo_);
            }
            int rg = (n0 >> 4) + rg_local;
            int kb = (k0 >> 5) + kb_local;
            size_t off = ((size_t)(rg * 16 + kb) * 64 + l) * 8;
            *(us8*)&whiT[off] = hv;
            *(us8*)&wloT[off] = lv;
        }
    }
}

// ------- GEMM1 (bf16 MFMA 3-pass, all operands pre-staged) + attn scalars | CSR build -------
__global__ __launch_bounds__(256) void k_gemm1(const ushort* __restrict__ Ahi,
                                               const ushort* __restrict__ Alo,
                                               const ushort* __restrict__ Bhi,
                                               const ushort* __restrict__ Blo,
                                               const float* __restrict__ att_src,
                                               const float* __restrict__ att_dst,
                                               const float* __restrict__ adj,
                                               __half* __restrict__ C,
                                               float* __restrict__ a_src,
                                               float* __restrict__ a_dst,
                                               int* __restrict__ row_cnt,
                                               int* __restrict__ col_idx) {
    __shared__ __align__(16) ushort smem[4][2048];
    __shared__ float s_s[2][64], s_d[2][64];
    __shared__ int cnt_s;
    int b = blockIdx.x;
    int t = threadIdx.x;
    if (b >= GBLKS) {
        // ---- CSR build (adds self loop); pure HBM stream overlapping the GEMM ----
        int i = b - GBLKS;
        if (t == 0) cnt_s = 0;
        __syncthreads();
        const float4* row = (const float4*)(adj + (size_t)i * N_NODES);
        int* cols = col_idx + (size_t)i * CAP;
#pragma unroll
        for (int it = 0; it < 4; ++it) {
            int idx4 = it * 256 + t;
            float4 v = row[idx4];
            int j0 = idx4 * 4;
            if (v.x != 0.f && j0 + 0 != i) { int p = atomicAdd(&cnt_s, 1); if (p < CAP - 1) cols[p] = j0 + 0; }
            if (v.y != 0.f && j0 + 1 != i) { int p = atomicAdd(&cnt_s, 1); if (p < CAP - 1) cols[p] = j0 + 1; }
            if (v.z != 0.f && j0 + 2 != i) { int p = atomicAdd(&cnt_s, 1); if (p < CAP - 1) cols[p] = j0 + 2; }
            if (v.w != 0.f && j0 + 3 != i) { int p = atomicAdd(&cnt_s, 1); if (p < CAP - 1) cols[p] = j0 + 3; }
        }
        __syncthreads();
        if (t == 0) {
            int p = min(cnt_s, CAP - 1);
            cols[p] = i;
            row_cnt[i] = p + 1;
        }
        return;
    }
    int w = t >> 6, lane = t & 63;
    int head = b >> 6;                 // XCD = b%8 = m%8: all 8 heads of an m-tile on one XCD
    int n0 = head * 64;
    int m0 = (b & 63) * 64;
    const ushort* src = (w == 0) ? Ahi : (w == 1) ? Alo : (w == 2) ? Bhi : Blo;
    int rg0 = ((w < 2) ? m0 : n0) >> 4;
    int mw = (w & 1) * 32, nw = (w >> 1) * 32;
    f32x4 acc[2][2] = {};
    for (int kb = 0; kb < 16; ++kb) {
#pragma unroll
        for (int g = 0; g < 4; ++g) {
            const ushort* gp = src + ((size_t)((rg0 + g) * 16 + kb) * 64 + lane) * 8;
            __builtin_amdgcn_global_load_lds(
                (const __attribute__((address_space(1))) void*)gp,
                (__attribute__((address_space(3))) void*)&smem[w][g * 512],
                16, 0, 0);
        }
        __syncthreads();
        bf16x8 ahi[2], alo[2], bhi[2], blo[2];
#pragma unroll
        for (int mi = 0; mi < 2; ++mi) {
            int g = (mw >> 4) + mi;
            ahi[mi] = __builtin_bit_cast(bf16x8, *(const us8*)&smem[0][g * 512 + lane * 8]);
            alo[mi] = __builtin_bit_cast(bf16x8, *(const us8*)&smem[1][g * 512 + lane * 8]);
        }
#pragma unroll
        for (int ni = 0; ni < 2; ++ni) {
            int g = (nw >> 4) + ni;
            bhi[ni] = __builtin_bit_cast(bf16x8, *(const us8*)&smem[2][g * 512 + lane * 8]);
            blo[ni] = __builtin_bit_cast(bf16x8, *(const us8*)&smem[3][g * 512 + lane * 8]);
        }
#pragma unroll
        for (int mi = 0; mi < 2; ++mi)
#pragma unroll
            for (int ni = 0; ni < 2; ++ni) {
                acc[mi][ni] = __builtin_amdgcn_mfma_f32_16x16x32_bf16(ahi[mi], bhi[ni], acc[mi][ni], 0, 0, 0);
                acc[mi][ni] = __builtin_amdgcn_mfma_f32_16x16x32_bf16(alo[mi], bhi[ni], acc[mi][ni], 0, 0, 0);
                acc[mi][ni] = __builtin_amdgcn_mfma_f32_16x16x32_bf16(ahi[mi], blo[ni], acc[mi][ni], 0, 0, 0);
            }
        __syncthreads();
    }
    int r0 = (lane >> 4) * 4;
    int cn = lane & 15;
    // fused attention scalars: per-row dot with att vectors (fp32 accs)
    float as0 = att_src[n0 + nw + cn],      as1 = att_src[n0 + nw + 16 + cn];
    float ad0 = att_dst[n0 + nw + cn],      ad1 = att_dst[n0 + nw + 16 + cn];
#pragma unroll
    for (int mi = 0; mi < 2; ++mi)
#pragma unroll
        for (int r = 0; r < 4; ++r) {
            float ps = acc[mi][0][r] * as0 + acc[mi][1][r] * as1;
            float pd = acc[mi][0][r] * ad0 + acc[mi][1][r] * ad1;
#pragma unroll
            for (int o = 1; o < 16; o <<= 1) {
                ps += __shfl_xor(ps, o, 64);
                pd += __shfl_xor(pd, o, 64);
            }
            if (cn == 0) {
                int row = mw + mi * 16 + r0 + r;
                s_s[w >> 1][row] = ps;
                s_d[w >> 1][row] = pd;
            }
        }
    // C store (fp16)
#pragma unroll
    for (int mi = 0; mi < 2; ++mi)
#pragma unroll
        for (int ni = 0; ni < 2; ++ni) {
            size_t base = (size_t)(m0 + mw + mi * 16 + r0) * HC + (n0 + nw + ni * 16 + cn);
#pragma unroll
            for (int r = 0; r < 4; ++r)
                C[base + (size_t)r * HC] = __float2half(acc[mi][ni][r]);
        }
    __syncthreads();
    if (t < 64) {
        a_src[(m0 + t) * H_HEADS + head] = s_s[0][t] + s_s[1][t];
        a_dst[(m0 + t) * H_HEADS + head] = s_d[0][t] + s_d[1][t];
    }
}

// ------- layer-1 softmax aggregation + bias + ELU + fused GEMM2 + layer-2 scalars -------
// 4 rows per block (one per wave), 64 threads/row, 8 halfs (16B dwordx4) per thread per neighbor.
__global__ __launch_bounds__(256) void k_agg1(const __half* __restrict__ hf,
                                              const float* __restrict__ a_src,
                                              const float* __restrict__ a_dst,
                                              const int* __restrict__ row_cnt,
                                              const int* __restrict__ col_idx,
                                              const float* __restrict__ b1,
                                              const float* __restrict__ W2,       // [512,16]
                                              const float* __restrict__ att_src2, // [16]
                                              const float* __restrict__ att_dst2, // [16]
                                              float* __restrict__ h2,
                                              float* __restrict__ a_src2,
                                              float* __restrict__ a_dst2) {
    int t = threadIdx.x;
    int r = t >> 6;            // row slot == wave
    int tt = t & 63;
    int i = blockIdx.x * 4 + r;
    __shared__ float wL[4][CAP][H_HEADS];   // 24 KB
    __shared__ int   colL[4][CAP];          // 3 KB
    __shared__ float denom[4][H_HEADS];
    __shared__ float ad[4][H_HEADS];
    __shared__ float elu_s[4][HC];          // 8 KB
    __shared__ float part[4][4][17];
    int cnt = row_cnt[i];
    if (tt < H_HEADS) ad[r][tt] = a_dst[i * H_HEADS + tt];
    for (int j = tt; j < cnt; j += 64) colL[r][j] = col_idx[(size_t)i * CAP + j];
    __syncthreads();
    for (int idx = tt; idx < cnt * H_HEADS; idx += 64) {
        int j = idx >> 3, h = idx & 7;
        float l = a_src[colL[r][j] * H_HEADS + h] + ad[r][h];
        l = (l > 0.f) ? l : NEG_SLOPE * l;
        wL[r][j][h] = __expf(l);
    }
    __syncthreads();
    {
        int h = tt >> 3, l8 = tt & 7;       // 8 threads per head
        float s = 0.f;
        for (int j = l8; j < cnt; j += 8) s += wL[r][j][h];
#pragma unroll
        for (int o = 4; o > 0; o >>= 1) s += __shfl_down(s, o, 8);
        if (l8 == 0) denom[r][h] = s;
    }
    __syncthreads();
    int e = tt * 8;            // 8 consecutive halfs (16B) per thread
    int h = tt >> 3;           // head = e>>6
    float a0 = 0.f, a1 = 0.f, a2 = 0.f, a3 = 0.f;
    float a4 = 0.f, a5 = 0.f, a6 = 0.f, a7 = 0.f;
    int j = 0;
    for (; j + 8 <= cnt; j += 8) {
#pragma unroll
        for (int u = 0; u < 8; ++u) {
            int c = colL[r][j + u];
            uint4 q = *(const uint4*)&hf[(size_t)c * HC + e];
            float2 f01 = __half22float2(__builtin_bit_cast(__half2, q.x));
            float2 f23 = __half22float2(__builtin_bit_cast(__half2, q.y));
            float2 f45 = __half22float2(__builtin_bit_cast(__half2, q.z));
            float2 f67 = __half22float2(__builtin_bit_cast(__half2, q.w));
            float wj = wL[r][j + u][h];
            a0 += wj * f01.x; a1 += wj * f01.y;
            a2 += wj * f23.x; a3 += wj * f23.y;
            a4 += wj * f45.x; a5 += wj * f45.y;
            a6 += wj * f67.x; a7 += wj * f67.y;
        }
    }
    for (; j < cnt; ++j) {
        int c = colL[r][j];
        uint4 q = *(const uint4*)&hf[(size_t)c * HC + e];
        float2 f01 = __half22float2(__builtin_bit_cast(__half2, q.x));
        float2 f23 = __half22float2(__builtin_bit_cast(__half2, q.y));
        float2 f45 = __half22float2(__builtin_bit_cast(__half2, q.z));
        float2 f67 = __half22float2(__builtin_bit_cast(__half2, q.w));
        float wj = wL[r][j][h];
        a0 += wj * f01.x; a1 += wj * f01.y;
        a2 += wj * f23.x; a3 += wj * f23.y;
        a4 += wj * f45.x; a5 += wj * f45.y;
        a6 += wj * f67.x; a7 += wj * f67.y;
    }
    float inv = 1.f / denom[r][h];
    float o0 = a0 * inv + b1[e];
    float o1 = a1 * inv + b1[e + 1];
    float o2 = a2 * inv + b1[e + 2];
    float o3 = a3 * inv + b1[e + 3];
    float o4 = a4 * inv + b1[e + 4];
    float o5 = a5 * inv + b1[e + 5];
    float o6 = a6 * inv + b1[e + 6];
    float o7 = a7 * inv + b1[e + 7];
    o0 = (o0 > 0.f) ? o0 : (__expf(o0) - 1.f);
    o1 = (o1 > 0.f) ? o1 : (__expf(o1) - 1.f);
    o2 = (o2 > 0.f) ? o2 : (__expf(o2) - 1.f);
    o3 = (o3 > 0.f) ? o3 : (__expf(o3) - 1.f);
    o4 = (o4 > 0.f) ? o4 : (__expf(o4) - 1.f);
    o5 = (o5 > 0.f) ? o5 : (__expf(o5) - 1.f);
    o6 = (o6 > 0.f) ? o6 : (__expf(o6) - 1.f);
    o7 = (o7 > 0.f) ? o7 : (__expf(o7) - 1.f);
    elu_s[r][e]     = o0;  elu_s[r][e + 1] = o1;
    elu_s[r][e + 2] = o2;  elu_s[r][e + 3] = o3;
    elu_s[r][e + 4] = o4;  elu_s[r][e + 5] = o5;
    elu_s[r][e + 6] = o6;  elu_s[r][e + 7] = o7;
    __syncthreads();
    // ---- fused GEMM2: h2[i,:] = elu_row @ W2  (512x16); 64 thr/row: kg 0..3 x c 0..15 ----
    {
        int kg = tt >> 4, c = tt & 15;
        float p = 0.f;
        const float* w2p = W2 + (size_t)kg * 128 * NCLS + c;
        const float* es  = &elu_s[r][kg * 128];
#pragma unroll 8
        for (int kk = 0; kk < 128; ++kk) p += es[kk] * w2p[kk * NCLS];
        part[r][kg][c] = p;
    }
    __syncthreads();
    if (tt < 16) {
        float s = 0.f;
#pragma unroll
        for (int g = 0; g < 4; ++g) s += part[r][g][tt];
        h2[(size_t)i * NCLS + tt] = s;
        float vs = s * att_src2[tt], vd = s * att_dst2[tt];
#pragma unroll
        for (int o = 8; o > 0; o >>= 1) {
            vs += __shfl_xor(vs, o, 16);
            vd += __shfl_xor(vd, o, 16);
        }
        if (tt == 0) { a_src2[i] = vs; a_dst2[i] = vd; }
    }
}

// ---------------- layer-2 softmax aggregation ----------------
__global__ __launch_bounds__(256) void k_agg2(const float* __restrict__ h2,
                                              const float* __restrict__ a_src2,
                                              const float* __restrict__ a_dst2,
                                              const int* __restrict__ row_cnt,
                                              const int* __restrict__ col_idx,
                                              const float* __restrict__ b2,
                                              float* __restrict__ out) {
    int t = threadIdx.x;
    int w = t >> 6, lane = t & 63;
    int i = blockIdx.x * 4 + w;
    __shared__ float ew[4][CAP];
    __shared__ int   colL[4][CAP];
    int cnt = row_cnt[i];
    float adi = a_dst2[i];
    float sum = 0.f;
    for (int j = lane; j < cnt; j += 64) {
        int col = col_idx[(size_t)i * CAP + j];
        colL[w][j] = col;
        float l = a_src2[col] + adi;
        l = (l > 0.f) ? l : NEG_SLOPE * l;
        float e = __expf(l);
        ew[w][j] = e;
        sum += e;
    }
#pragma unroll
    for (int o = 32; o > 0; o >>= 1) sum += __shfl_xor(sum, o, 64);
    int q = lane >> 4, c = lane & 15;
    float acc = 0.f;
    for (int j = q; j < cnt; j += 4)
        acc += ew[w][j] * h2[(size_t)colL[w][j] * NCLS + c];
    acc += __shfl_down(acc, 32, 64);
    acc += __shfl_down(acc, 16, 64);
    if (lane < NCLS)
        out[(size_t)i * NCLS + lane] = acc / sum + b2[lane];
}

extern "C" void kernel_launch(void* const* d_in, const int* in_sizes, int n_in,
                              void* d_out, int out_size, void* d_ws, size_t ws_size,
                              hipStream_t stream) {
    const float* x        = (const float*)d_in[0];
    const float* adj      = (const float*)d_in[1];
    const float* W1       = (const float*)d_in[2];
    const float* att_src1 = (const float*)d_in[3];
    const float* att_dst1 = (const float*)d_in[4];
    const float* b1       = (const float*)d_in[5];
    const float* W2       = (const float*)d_in[6];
    const float* att_src2 = (const float*)d_in[7];
    const float* att_dst2 = (const float*)d_in[8];
    const float* b2       = (const float*)d_in[9];
    float* out = (float*)d_out;

    char* ws = (char*)d_ws;
    int*    row_cnt = (int*)ws;     ws += (size_t)N_NODES * 4;
    int*    col_idx = (int*)ws;     ws += (size_t)N_NODES * CAP * 4;
    __half* h1f     = (__half*)ws;  ws += (size_t)N_NODES * HC * 2;
    float*  a_src   = (float*)ws;   ws += (size_t)N_NODES * H_HEADS * 4;
    float*  a_dst   = (float*)ws;   ws += (size_t)N_NODES * H_HEADS * 4;
    float*  h2      = (float*)ws;   ws += (size_t)N_NODES * NCLS * 4;
    float*  as2     = (float*)ws;   ws += (size_t)N_NODES * 4;
    float*  ad2     = (float*)ws;   ws += (size_t)N_NODES * 4;
    ushort* x_hi    = (ushort*)ws;  ws += (size_t)N_NODES * F_IN * 2;
    ushort* x_lo    = (ushort*)ws;  ws += (size_t)N_NODES * F_IN * 2;
    ushort* w_hiT   = (ushort*)ws;  ws += (size_t)F_IN * HC * 2;
    ushort* w_loT   = (ushort*)ws;  ws += (size_t)F_IN * HC * 2;

    hipLaunchKernelGGL(k_split, dim3(XBLKS + WBLKS), dim3(256), 0, stream,
                       x, W1, x_hi, x_lo, w_hiT, w_loT);
    hipLaunchKernelGGL(k_gemm1, dim3(GBLKS + N_NODES), dim3(256), 0, stream,
                       x_hi, x_lo, w_hiT, w_loT, att_src1, att_dst1, adj,
                       h1f, a_src, a_dst, row_cnt, col_idx);
    hipLaunchKernelGGL(k_agg1, dim3(N_NODES / 4), dim3(256), 0, stream,
                       h1f, a_src, a_dst, row_cnt, col_idx, b1,
                       W2, att_src2, att_dst2, h2, as2, ad2);
    hipLaunchKernelGGL(k_agg2, dim3(N_NODES / 4), dim3(256), 0, stream,
                       h2, as2, ad2, row_cnt, col_idx, b2, out);
}